// Round 5
// baseline (545.704 us; speedup 1.0000x reference)
//
#include <hip/hip_runtime.h>
#include <math.h>

using short8 = __attribute__((ext_vector_type(8))) short;
using f32x4  = __attribute__((ext_vector_type(4))) float;

#define NBLKS 512
#define BPAD  800   // padded bucket count (nbuck <= 800)
#define EB 8

__device__ __forceinline__ unsigned short f2bf(float f) {
    unsigned u = __float_as_uint(f);
    unsigned r = u + 0x7FFF + ((u >> 16) & 1);   // round-to-nearest-even
    return (unsigned short)(r >> 16);
}

// ---------------- edge dtype detect ----------------

__global__ void detect64_kernel(const int* __restrict__ ei, int E, int* __restrict__ flag) {
    __shared__ int any;
    if (threadIdx.x == 0) any = 0;
    __syncthreads();
    for (int i = threadIdx.x; i < 1024; i += 256) {
        if (ei[2 * i + 1] != 0) { any = 1; break; }
    }
    __syncthreads();
    if (threadIdx.x == 0) *flag = (any ? 0 : 1);  // 1 => int64
}

// ---------------- CSR build: two-level counting sort, zero global atomics ----------------

__global__ __launch_bounds__(256) void binA_kernel(
    const int* __restrict__ ei, int E, int N, const int* __restrict__ flag,
    int nbuck, int* __restrict__ hist, int chunk) {
    __shared__ int lh[BPAD];
    for (int i = threadIdx.x; i < nbuck; i += 256) lh[i] = 0;
    __syncthreads();
    int is64 = *flag;
    int Etot = E + N;
    int beg = blockIdx.x * chunk, end = min(Etot, beg + chunk);
    for (int i = beg + threadIdx.x; i < end; i += 256) {
        int d = (i < E) ? (is64 ? ei[2 * (E + i)] : ei[E + i]) : (i - E);
        atomicAdd(&lh[d >> 7], 1);
    }
    __syncthreads();
    for (int i = threadIdx.x; i < nbuck; i += 256) hist[blockIdx.x * BPAD + i] = lh[i];
}

__global__ void scanBlocks_kernel(int* __restrict__ hist, int nbuck, int* __restrict__ bucketTotal) {
    int bin = blockIdx.x * 256 + threadIdx.x;
    if (bin >= nbuck) return;
    int run = 0;
    for (int b = 0; b < NBLKS; b++) {
        int v = hist[b * BPAD + bin];
        hist[b * BPAD + bin] = run;
        run += v;
    }
    bucketTotal[bin] = run;
}

__global__ void scanBucket_kernel(const int* __restrict__ bucketTotal, int nbuck,
                                  int* __restrict__ bucketBase) {
    __shared__ int s[1024];
    int t = threadIdx.x;
    int v = (t < nbuck) ? bucketTotal[t] : 0;
    s[t] = v;
    __syncthreads();
    for (int off = 1; off < 1024; off <<= 1) {
        int x = (t >= off) ? s[t - off] : 0;
        __syncthreads();
        s[t] += x;
        __syncthreads();
    }
    if (t < nbuck) bucketBase[t] = s[t] - v;
    if (t == nbuck - 1) bucketBase[nbuck] = s[t];
}

__global__ __launch_bounds__(256) void binB_kernel(
    const int* __restrict__ ei, int E, int N, const int* __restrict__ flag,
    int nbuck, const int* __restrict__ hist, const int* __restrict__ bucketBase,
    int* __restrict__ tmp, int chunk) {
    __shared__ int cur[BPAD];
    for (int i = threadIdx.x; i < nbuck; i += 256)
        cur[i] = bucketBase[i] + hist[blockIdx.x * BPAD + i];
    __syncthreads();
    int is64 = *flag;
    int Etot = E + N;
    int beg = blockIdx.x * chunk, end = min(Etot, beg + chunk);
    for (int i = beg + threadIdx.x; i < end; i += 256) {
        int s, d;
        if (i < E) {
            if (is64) { s = ei[2 * i]; d = ei[2 * (E + i)]; }
            else      { s = ei[i];     d = ei[E + i]; }
        } else { s = i - E; d = i - E; }
        int pos = atomicAdd(&cur[d >> 7], 1);
        tmp[pos] = ((d & 127) << 17) | s;   // src < 2^17
    }
}

__global__ __launch_bounds__(256) void binC_kernel(
    const int* __restrict__ tmp, const int* __restrict__ bucketBase, int nbuck,
    int N, int Etot, int* __restrict__ rowptr, int* __restrict__ col) {
    __shared__ int lh[128];
    __shared__ int cur[128];
    int g = blockIdx.x;
    int t = threadIdx.x;
    int beg = bucketBase[g], end = bucketBase[g + 1];
    if (t < 128) lh[t] = 0;
    __syncthreads();
    for (int i = beg + t; i < end; i += 256) atomicAdd(&lh[tmp[i] >> 17], 1);
    __syncthreads();
    int c = (t < 128) ? lh[t] : 0;
    for (int off = 1; off < 128; off <<= 1) {
        int x = 0;
        if (t < 128 && t >= off) x = lh[t - off];
        __syncthreads();
        if (t < 128) lh[t] += x;
        __syncthreads();
    }
    if (t < 128) {
        int excl = lh[t] - c;
        cur[t] = beg + excl;
        int node = g * 128 + t;
        if (node < N) rowptr[node] = beg + excl;
    }
    if (g == 0 && t == 0) rowptr[N] = Etot;
    if (g == 0 && t < 8) col[Etot + t] = 0;   // pad so agg can read 7 past end safely
    __syncthreads();
    for (int i = beg + t; i < end; i += 256) {
        int v = tmp[i];
        int pos = atomicAdd(&cur[v >> 17], 1);
        col[pos] = v & 0x1FFFF;
    }
}

// ---------------- GEMM 1 (MFMA bf16): h1 = x @ W1, fused e_src/e_dst ----------------

__global__ __launch_bounds__(256) void gemm1_mfma_kernel(
    const float* __restrict__ x, const float* __restrict__ W,
    const float* __restrict__ asrc, const float* __restrict__ adst,
    float* __restrict__ h, float* __restrict__ es, float* __restrict__ ed, int N) {
    __shared__ __align__(16) unsigned short A_lds[128 * 40];
    __shared__ __align__(16) unsigned short B_lds[64 * 40];
    const int tx = threadIdx.x;
    const int wv = tx >> 6;
    const int lane = tx & 63;
    const int l15 = lane & 15;
    const int quad = lane >> 4;
    const int rowBase = blockIdx.x * 128;

    f32x4 acc[2][4];
#pragma unroll
    for (int rt = 0; rt < 2; rt++)
#pragma unroll
        for (int ct = 0; ct < 4; ct++) acc[rt][ct] = (f32x4){0.f, 0.f, 0.f, 0.f};

    const int kq = tx & 7;
    const int r0 = tx >> 3;
    const int colB = tx & 63;
    const int kkb = (tx >> 6) * 8;

    for (int k0 = 0; k0 < 320; k0 += 32) {
        bool kvalid = (k0 + kq * 4 + 4 <= 300);
#pragma unroll
        for (int p = 0; p < 4; p++) {
            int row = p * 32 + r0;
            int grow = rowBase + row;
            float4 v = make_float4(0.f, 0.f, 0.f, 0.f);
            if (kvalid && grow < N) v = *(const float4*)&x[(size_t)grow * 300 + k0 + kq * 4];
            *(ushort4*)&A_lds[row * 40 + kq * 4] =
                make_ushort4(f2bf(v.x), f2bf(v.y), f2bf(v.z), f2bf(v.w));
        }
        {
            unsigned short t0, t1, t2, t3, t4, t5, t6, t7;
            float v;
            v = (k0 + kkb + 0 < 300) ? W[(size_t)(k0 + kkb + 0) * 64 + colB] : 0.f; t0 = f2bf(v);
            v = (k0 + kkb + 1 < 300) ? W[(size_t)(k0 + kkb + 1) * 64 + colB] : 0.f; t1 = f2bf(v);
            v = (k0 + kkb + 2 < 300) ? W[(size_t)(k0 + kkb + 2) * 64 + colB] : 0.f; t2 = f2bf(v);
            v = (k0 + kkb + 3 < 300) ? W[(size_t)(k0 + kkb + 3) * 64 + colB] : 0.f; t3 = f2bf(v);
            v = (k0 + kkb + 4 < 300) ? W[(size_t)(k0 + kkb + 4) * 64 + colB] : 0.f; t4 = f2bf(v);
            v = (k0 + kkb + 5 < 300) ? W[(size_t)(k0 + kkb + 5) * 64 + colB] : 0.f; t5 = f2bf(v);
            v = (k0 + kkb + 6 < 300) ? W[(size_t)(k0 + kkb + 6) * 64 + colB] : 0.f; t6 = f2bf(v);
            v = (k0 + kkb + 7 < 300) ? W[(size_t)(k0 + kkb + 7) * 64 + colB] : 0.f; t7 = f2bf(v);
            *(ushort4*)&B_lds[colB * 40 + kkb]     = make_ushort4(t0, t1, t2, t3);
            *(ushort4*)&B_lds[colB * 40 + kkb + 4] = make_ushort4(t4, t5, t6, t7);
        }
        __syncthreads();
        short8 af[2], bfr[4];
#pragma unroll
        for (int rt = 0; rt < 2; rt++)
            af[rt] = *(const short8*)&A_lds[(wv * 32 + rt * 16 + l15) * 40 + quad * 8];
#pragma unroll
        for (int ct = 0; ct < 4; ct++)
            bfr[ct] = *(const short8*)&B_lds[(ct * 16 + l15) * 40 + quad * 8];
#pragma unroll
        for (int rt = 0; rt < 2; rt++)
#pragma unroll
            for (int ct = 0; ct < 4; ct++)
                acc[rt][ct] = __builtin_amdgcn_mfma_f32_16x16x32_bf16(af[rt], bfr[ct], acc[rt][ct], 0, 0, 0);
        __syncthreads();
    }

    float as_v[4], ad_v[4];
#pragma unroll
    for (int ct = 0; ct < 4; ct++) {
        as_v[ct] = asrc[ct * 16 + l15];
        ad_v[ct] = adst[ct * 16 + l15];
    }
#pragma unroll
    for (int rt = 0; rt < 2; rt++) {
#pragma unroll
        for (int reg = 0; reg < 4; reg++) {
            int row = rowBase + wv * 32 + rt * 16 + quad * 4 + reg;
            bool ok = (row < N);
#pragma unroll
            for (int ct = 0; ct < 4; ct++) {
                float v = acc[rt][ct][reg];
                if (ok) h[(size_t)row * 64 + ct * 16 + l15] = v;
                float ps = v * as_v[ct];
                float pd = v * ad_v[ct];
                ps += __shfl_xor(ps, 1); ps += __shfl_xor(ps, 2); ps += __shfl_xor(ps, 4);
                pd += __shfl_xor(pd, 1); pd += __shfl_xor(pd, 2); pd += __shfl_xor(pd, 4);
                if ((lane & 7) == 0 && ok) {
                    int head = 2 * ct + ((lane >> 3) & 1);
                    es[row * 8 + head] = ps;
                    ed[row * 8 + head] = pd;
                }
            }
        }
    }
}

// ---------------- GEMM 2 (MFMA bf16): h2 = h1p @ W2, fused scalar e_src/e_dst ----------------

__global__ __launch_bounds__(256) void gemm2_mfma_kernel(
    const float* __restrict__ xin, const float* __restrict__ W,
    const float* __restrict__ asrc, const float* __restrict__ adst,
    float* __restrict__ h, float* __restrict__ es, float* __restrict__ ed, int N) {
    __shared__ __align__(16) unsigned short A_lds[128 * 72];
    __shared__ __align__(16) unsigned short B_lds[64 * 72];
    const int tx = threadIdx.x;
    const int wv = tx >> 6;
    const int lane = tx & 63;
    const int l15 = lane & 15;
    const int quad = lane >> 4;
    const int rowBase = blockIdx.x * 128;

    f32x4 acc[2][4];
#pragma unroll
    for (int rt = 0; rt < 2; rt++)
#pragma unroll
        for (int ct = 0; ct < 4; ct++) acc[rt][ct] = (f32x4){0.f, 0.f, 0.f, 0.f};

    // stage B: full 64x64 (transposed into [col][k], stride 72)
    {
        int colB = tx & 63;
        int kk = (tx >> 6) * 16;
#pragma unroll
        for (int j = 0; j < 16; j++)
            B_lds[colB * 72 + kk + j] = f2bf(W[(size_t)(kk + j) * 64 + colB]);
    }
    // stage A: 128 rows x 64 k
    {
        int kq = tx & 15, r0 = tx >> 4;
#pragma unroll
        for (int p = 0; p < 8; p++) {
            int row = p * 16 + r0;
            int grow = rowBase + row;
            float4 v = make_float4(0.f, 0.f, 0.f, 0.f);
            if (grow < N) v = *(const float4*)&xin[(size_t)grow * 64 + kq * 4];
            *(ushort4*)&A_lds[row * 72 + kq * 4] =
                make_ushort4(f2bf(v.x), f2bf(v.y), f2bf(v.z), f2bf(v.w));
        }
    }
    __syncthreads();
#pragma unroll
    for (int c = 0; c < 2; c++) {
        short8 af[2], bfr[4];
#pragma unroll
        for (int rt = 0; rt < 2; rt++)
            af[rt] = *(const short8*)&A_lds[(wv * 32 + rt * 16 + l15) * 72 + quad * 8 + c * 32];
#pragma unroll
        for (int ct = 0; ct < 4; ct++)
            bfr[ct] = *(const short8*)&B_lds[(ct * 16 + l15) * 72 + quad * 8 + c * 32];
#pragma unroll
        for (int rt = 0; rt < 2; rt++)
#pragma unroll
            for (int ct = 0; ct < 4; ct++)
                acc[rt][ct] = __builtin_amdgcn_mfma_f32_16x16x32_bf16(af[rt], bfr[ct], acc[rt][ct], 0, 0, 0);
    }

    float as_v[4], ad_v[4];
#pragma unroll
    for (int ct = 0; ct < 4; ct++) {
        as_v[ct] = asrc[ct * 16 + l15];
        ad_v[ct] = adst[ct * 16 + l15];
    }
#pragma unroll
    for (int rt = 0; rt < 2; rt++) {
#pragma unroll
        for (int reg = 0; reg < 4; reg++) {
            int row = rowBase + wv * 32 + rt * 16 + quad * 4 + reg;
            bool ok = (row < N);
            float ps = 0.f, pd = 0.f;
#pragma unroll
            for (int ct = 0; ct < 4; ct++) {
                float v = acc[rt][ct][reg];
                if (ok) h[(size_t)row * 64 + ct * 16 + l15] = v;
                ps = fmaf(v, as_v[ct], ps);
                pd = fmaf(v, ad_v[ct], pd);
            }
            ps += __shfl_xor(ps, 1); ps += __shfl_xor(ps, 2);
            ps += __shfl_xor(ps, 4); ps += __shfl_xor(ps, 8);
            pd += __shfl_xor(pd, 1); pd += __shfl_xor(pd, 2);
            pd += __shfl_xor(pd, 4); pd += __shfl_xor(pd, 8);
            if (l15 == 0 && ok) { es[row] = ps; ed[row] = pd; }
        }
    }
}

// ---------------- alpha precompute: per-(node,head) softmax weights ----------------
// Layer 1: thread = (node,head); 2 passes (max, then exp+sum); w stored bf16; 1/l stored.

__global__ __launch_bounds__(256) void alpha1_kernel(
    const int* __restrict__ rowptr, const int* __restrict__ col,
    const float* __restrict__ es, const float* __restrict__ ed,
    unsigned short* __restrict__ w1a, float* __restrict__ rden, int N) {
    int tid = blockIdx.x * 256 + threadIdx.x;
    int node = tid >> 3, head = tid & 7;
    if (node >= N) return;
    int beg = rowptr[node], end = rowptr[node + 1];
    float edv = ed[node * 8 + head];
    float m = -1e30f;
    for (int e = beg; e < end; e++) {
        int s = col[e];
        float v = es[s * 8 + head] + edv;
        v = (v > 0.f) ? v : 0.2f * v;
        m = fmaxf(m, v);
    }
    float l = 0.f;
    for (int e = beg; e < end; e++) {
        int s = col[e];
        float v = es[s * 8 + head] + edv;
        v = (v > 0.f) ? v : 0.2f * v;
        float wj = __expf(v - m);
        l += wj;
        w1a[e * 8 + head] = f2bf(wj);
    }
    rden[node * 8 + head] = 1.f / l;
}

__global__ __launch_bounds__(256) void alpha2_kernel(
    const int* __restrict__ rowptr, const int* __restrict__ col,
    const float* __restrict__ es, const float* __restrict__ ed,
    float* __restrict__ w2a, float* __restrict__ rden, int N) {
    int node = blockIdx.x * 256 + threadIdx.x;
    if (node >= N) return;
    int beg = rowptr[node], end = rowptr[node + 1];
    float edv = ed[node];
    float m = -1e30f;
    for (int e = beg; e < end; e++) {
        float v = es[col[e]] + edv;
        v = (v > 0.f) ? v : 0.2f * v;
        m = fmaxf(m, v);
    }
    float l = 0.f;
    for (int e = beg; e < end; e++) {
        float v = es[col[e]] + edv;
        v = (v > 0.f) ? v : 0.2f * v;
        float wj = __expf(v - m);
        l += wj;
        w2a[e] = wj;
    }
    rden[node] = 1.f / l;
}

// ---------------- gather-only aggregations ----------------

__global__ __launch_bounds__(256) void agg1g_kernel(
    const int* __restrict__ rowptr, const int* __restrict__ col,
    const float* __restrict__ h, const unsigned short* __restrict__ w1a,
    const float* __restrict__ rden, const float* __restrict__ b,
    float* __restrict__ out, int N) {
    int node = blockIdx.x * 4 + (threadIdx.x >> 6);
    int lane = threadIdx.x & 63;
    if (node >= N) return;
    int hh = lane >> 3;
    int beg = rowptr[node], end = rowptr[node + 1];
    float rinv = rden[node * 8 + hh];
    float acc = 0.f;
    for (int i = beg; i < end; i += EB) {
        int ss[EB];
        float wv[EB], hv[EB];
#pragma unroll
        for (int j = 0; j < EB; j++) ss[j] = col[i + j];              // col padded by 8
#pragma unroll
        for (int j = 0; j < EB; j++) {
            unsigned wr = w1a[(i + j) * 8 + hh];
            wv[j] = __uint_as_float(wr << 16);
        }
#pragma unroll
        for (int j = 0; j < EB; j++) hv[j] = h[(size_t)ss[j] * 64 + lane];
#pragma unroll
        for (int j = 0; j < EB; j++) wv[j] = (i + j < end) ? wv[j] : 0.f;
#pragma unroll
        for (int j = 0; j < EB; j++) acc = fmaf(wv[j], hv[j], acc);
    }
    float o = acc * rinv + b[lane];
    o = (o > 0.f) ? o : expm1f(o);
    out[(size_t)node * 64 + lane] = o;
}

__global__ __launch_bounds__(256) void agg2g_kernel(
    const int* __restrict__ rowptr, const int* __restrict__ col,
    const float* __restrict__ h, const float* __restrict__ w2a,
    const float* __restrict__ rden, const float* __restrict__ b,
    float* __restrict__ out, int N) {
    int node = blockIdx.x * 4 + (threadIdx.x >> 6);
    int lane = threadIdx.x & 63;
    if (node >= N) return;
    int beg = rowptr[node], end = rowptr[node + 1];
    float rinv = rden[node];
    float acc = 0.f;
    for (int i = beg; i < end; i += EB) {
        int ss[EB];
        float wv[EB], hv[EB];
#pragma unroll
        for (int j = 0; j < EB; j++) ss[j] = col[i + j];
#pragma unroll
        for (int j = 0; j < EB; j++) wv[j] = w2a[i + j];              // tmp buffer padded
#pragma unroll
        for (int j = 0; j < EB; j++) hv[j] = h[(size_t)ss[j] * 64 + lane];
#pragma unroll
        for (int j = 0; j < EB; j++) wv[j] = (i + j < end) ? wv[j] : 0.f;
#pragma unroll
        for (int j = 0; j < EB; j++) acc = fmaf(wv[j], hv[j], acc);
    }
    float o = acc * rinv + b[lane];
    float M = o;
    for (int off = 32; off > 0; off >>= 1) M = fmaxf(M, __shfl_xor(M, off));
    float se = __expf(o - M);
    for (int off = 32; off > 0; off >>= 1) se += __shfl_xor(se, off);
    out[(size_t)node * 64 + lane] = o - M - logf(se);
}

// ---------------- launch ----------------

extern "C" void kernel_launch(void* const* d_in, const int* in_sizes, int n_in,
                              void* d_out, int out_size, void* d_ws, size_t ws_size,
                              hipStream_t stream) {
    const float* x   = (const float*)d_in[0];
    const int*   ei  = (const int*)d_in[1];
    const float* W1  = (const float*)d_in[2];
    const float* as1 = (const float*)d_in[3];
    const float* ad1 = (const float*)d_in[4];
    const float* b1  = (const float*)d_in[5];
    const float* W2  = (const float*)d_in[6];
    const float* as2 = (const float*)d_in[7];
    const float* ad2 = (const float*)d_in[8];
    const float* b2  = (const float*)d_in[9];
    const int N = in_sizes[0] / 300;
    const int E = in_sizes[1] / 2;
    const int Etot = E + N;
    const int nbuck = (N + 127) >> 7;   // <= 800
    (void)n_in; (void)out_size; (void)ws_size;

    char* w = (char*)d_ws;
    auto alloc = [&](size_t bytes) -> char* {
        char* p = w;
        w += (bytes + 255) & ~(size_t)255;
        return p;
    };
    int*   flag        = (int*)alloc(256);
    int*   hist        = (int*)alloc((size_t)NBLKS * BPAD * 4);
    int*   bucketTotal = (int*)alloc((size_t)(BPAD + 1) * 4);
    int*   bucketBase  = (int*)alloc((size_t)(BPAD + 1) * 4);
    int*   tmp         = (int*)alloc((size_t)(Etot + 8) * 4);   // reused as w2a
    int*   rowptr      = (int*)alloc((size_t)(N + 1) * 4);
    int*   col         = (int*)alloc((size_t)(Etot + 8) * 4);
    float* h1          = (float*)alloc((size_t)N * 64 * 4);
    float* h1p         = (float*)alloc((size_t)N * 64 * 4);
    float* es1         = (float*)alloc((size_t)N * 8 * 4);
    float* ed1         = (float*)alloc((size_t)N * 8 * 4);
    float* es2         = (float*)alloc((size_t)N * 4);
    float* ed2         = (float*)alloc((size_t)N * 4);
    unsigned short* w1a = (unsigned short*)alloc((size_t)(Etot + 8) * 8 * 2);
    float* rden1       = (float*)alloc((size_t)N * 8 * 4);
    float* rden2       = (float*)alloc((size_t)N * 4);
    float* h2 = h1;                 // h1 dead after agg1
    float* w2a = (float*)tmp;       // tmp dead after binC

    detect64_kernel<<<1, 256, 0, stream>>>(ei, E, flag);

    int chunk = (Etot + NBLKS - 1) / NBLKS;
    binA_kernel<<<NBLKS, 256, 0, stream>>>(ei, E, N, flag, nbuck, hist, chunk);
    scanBlocks_kernel<<<(nbuck + 255) / 256, 256, 0, stream>>>(hist, nbuck, bucketTotal);
    scanBucket_kernel<<<1, 1024, 0, stream>>>(bucketTotal, nbuck, bucketBase);
    binB_kernel<<<NBLKS, 256, 0, stream>>>(ei, E, N, flag, nbuck, hist, bucketBase, tmp, chunk);
    binC_kernel<<<nbuck, 256, 0, stream>>>(tmp, bucketBase, nbuck, N, Etot, rowptr, col);

    gemm1_mfma_kernel<<<(N + 127) / 128, 256, 0, stream>>>(x, W1, as1, ad1, h1, es1, ed1, N);
    alpha1_kernel<<<(N * 8 + 255) / 256, 256, 0, stream>>>(rowptr, col, es1, ed1, w1a, rden1, N);
    agg1g_kernel<<<(N + 3) / 4, 256, 0, stream>>>(rowptr, col, h1, w1a, rden1, b1, h1p, N);
    gemm2_mfma_kernel<<<(N + 127) / 128, 256, 0, stream>>>(h1p, W2, as2, ad2, h2, es2, ed2, N);
    alpha2_kernel<<<(N + 255) / 256, 256, 0, stream>>>(rowptr, col, es2, ed2, w2a, rden2, N);
    agg2g_kernel<<<(N + 3) / 4, 256, 0, stream>>>(rowptr, col, h2, w2a, rden2, b2, (float*)d_out, N);
}

// Round 6
// 479.544 us; speedup vs baseline: 1.1380x; 1.1380x over previous
//
#include <hip/hip_runtime.h>
#include <math.h>

using short8  = __attribute__((ext_vector_type(8))) short;
using ushort8 = __attribute__((ext_vector_type(8))) unsigned short;
using f32x4   = __attribute__((ext_vector_type(4))) float;

#define NBLKS 512
#define BPAD  800   // padded bucket count (nbuck <= 800)
#define EB 8

__device__ __forceinline__ unsigned short f2bf(float f) {
    unsigned u = __float_as_uint(f);
    unsigned r = u + 0x7FFF + ((u >> 16) & 1);   // round-to-nearest-even
    return (unsigned short)(r >> 16);
}
__device__ __forceinline__ float bf2f(unsigned short v) {
    return __uint_as_float((unsigned)v << 16);
}

// ---------------- edge dtype detect ----------------

__global__ void detect64_kernel(const int* __restrict__ ei, int E, int* __restrict__ flag) {
    __shared__ int any;
    if (threadIdx.x == 0) any = 0;
    __syncthreads();
    for (int i = threadIdx.x; i < 1024; i += 256) {
        if (ei[2 * i + 1] != 0) { any = 1; break; }
    }
    __syncthreads();
    if (threadIdx.x == 0) *flag = (any ? 0 : 1);  // 1 => int64
}

// ---------------- CSR build: two-level counting sort, zero global atomics ----------------

__global__ __launch_bounds__(256) void binA_kernel(
    const int* __restrict__ ei, int E, int N, const int* __restrict__ flag,
    int nbuck, int* __restrict__ hist, int chunk) {
    __shared__ int lh[BPAD];
    for (int i = threadIdx.x; i < nbuck; i += 256) lh[i] = 0;
    __syncthreads();
    int is64 = *flag;
    int Etot = E + N;
    int beg = blockIdx.x * chunk, end = min(Etot, beg + chunk);
    for (int i = beg + threadIdx.x; i < end; i += 256) {
        int d = (i < E) ? (is64 ? ei[2 * (E + i)] : ei[E + i]) : (i - E);
        atomicAdd(&lh[d >> 7], 1);
    }
    __syncthreads();
    for (int i = threadIdx.x; i < nbuck; i += 256) hist[blockIdx.x * BPAD + i] = lh[i];
}

__global__ void scanBlocks_kernel(int* __restrict__ hist, int nbuck, int* __restrict__ bucketTotal) {
    int bin = blockIdx.x * 256 + threadIdx.x;
    if (bin >= nbuck) return;
    int run = 0;
    for (int b = 0; b < NBLKS; b++) {
        int v = hist[b * BPAD + bin];
        hist[b * BPAD + bin] = run;
        run += v;
    }
    bucketTotal[bin] = run;
}

__global__ void scanBucket_kernel(const int* __restrict__ bucketTotal, int nbuck,
                                  int* __restrict__ bucketBase) {
    __shared__ int s[1024];
    int t = threadIdx.x;
    int v = (t < nbuck) ? bucketTotal[t] : 0;
    s[t] = v;
    __syncthreads();
    for (int off = 1; off < 1024; off <<= 1) {
        int x = (t >= off) ? s[t - off] : 0;
        __syncthreads();
        s[t] += x;
        __syncthreads();
    }
    if (t < nbuck) bucketBase[t] = s[t] - v;
    if (t == nbuck - 1) bucketBase[nbuck] = s[t];
}

__global__ __launch_bounds__(256) void binB_kernel(
    const int* __restrict__ ei, int E, int N, const int* __restrict__ flag,
    int nbuck, const int* __restrict__ hist, const int* __restrict__ bucketBase,
    int* __restrict__ tmp, int chunk) {
    __shared__ int cur[BPAD];
    for (int i = threadIdx.x; i < nbuck; i += 256)
        cur[i] = bucketBase[i] + hist[blockIdx.x * BPAD + i];
    __syncthreads();
    int is64 = *flag;
    int Etot = E + N;
    int beg = blockIdx.x * chunk, end = min(Etot, beg + chunk);
    for (int i = beg + threadIdx.x; i < end; i += 256) {
        int s, d;
        if (i < E) {
            if (is64) { s = ei[2 * i]; d = ei[2 * (E + i)]; }
            else      { s = ei[i];     d = ei[E + i]; }
        } else { s = i - E; d = i - E; }
        int pos = atomicAdd(&cur[d >> 7], 1);
        tmp[pos] = ((d & 127) << 17) | s;   // src < 2^17
    }
}

__global__ __launch_bounds__(256) void binC_kernel(
    const int* __restrict__ tmp, const int* __restrict__ bucketBase, int nbuck,
    int N, int Etot, int* __restrict__ rowptr, int* __restrict__ col) {
    __shared__ int lh[128];
    __shared__ int cur[128];
    int g = blockIdx.x;
    int t = threadIdx.x;
    int beg = bucketBase[g], end = bucketBase[g + 1];
    if (t < 128) lh[t] = 0;
    __syncthreads();
    for (int i = beg + t; i < end; i += 256) atomicAdd(&lh[tmp[i] >> 17], 1);
    __syncthreads();
    int c = (t < 128) ? lh[t] : 0;
    for (int off = 1; off < 128; off <<= 1) {
        int x = 0;
        if (t < 128 && t >= off) x = lh[t - off];
        __syncthreads();
        if (t < 128) lh[t] += x;
        __syncthreads();
    }
    if (t < 128) {
        int excl = lh[t] - c;
        cur[t] = beg + excl;
        int node = g * 128 + t;
        if (node < N) rowptr[node] = beg + excl;
    }
    if (g == 0 && t == 0) rowptr[N] = Etot;
    if (g == 0 && t < 16) col[Etot + t] = 0;   // pad so agg can read past end safely
    __syncthreads();
    for (int i = beg + t; i < end; i += 256) {
        int v = tmp[i];
        int pos = atomicAdd(&cur[v >> 17], 1);
        col[pos] = v & 0x1FFFF;
    }
}

// ---------------- GEMM 1 (MFMA bf16): h1(bf16) = x @ W1, fused e_src/e_dst ----------------

__global__ __launch_bounds__(256) void gemm1_mfma_kernel(
    const float* __restrict__ x, const float* __restrict__ W,
    const float* __restrict__ asrc, const float* __restrict__ adst,
    unsigned short* __restrict__ hbf, float* __restrict__ es, float* __restrict__ ed, int N) {
    __shared__ __align__(16) unsigned short A_lds[128 * 40];
    __shared__ __align__(16) unsigned short B_lds[64 * 40];
    const int tx = threadIdx.x;
    const int wv = tx >> 6;
    const int lane = tx & 63;
    const int l15 = lane & 15;
    const int quad = lane >> 4;
    const int rowBase = blockIdx.x * 128;

    f32x4 acc[2][4];
#pragma unroll
    for (int rt = 0; rt < 2; rt++)
#pragma unroll
        for (int ct = 0; ct < 4; ct++) acc[rt][ct] = (f32x4){0.f, 0.f, 0.f, 0.f};

    const int kq = tx & 7;
    const int r0 = tx >> 3;
    const int colB = tx & 63;
    const int kkb = (tx >> 6) * 8;

    for (int k0 = 0; k0 < 320; k0 += 32) {
        bool kvalid = (k0 + kq * 4 + 4 <= 300);
#pragma unroll
        for (int p = 0; p < 4; p++) {
            int row = p * 32 + r0;
            int grow = rowBase + row;
            float4 v = make_float4(0.f, 0.f, 0.f, 0.f);
            if (kvalid && grow < N) v = *(const float4*)&x[(size_t)grow * 300 + k0 + kq * 4];
            *(ushort4*)&A_lds[row * 40 + kq * 4] =
                make_ushort4(f2bf(v.x), f2bf(v.y), f2bf(v.z), f2bf(v.w));
        }
        {
            unsigned short t0, t1, t2, t3, t4, t5, t6, t7;
            float v;
            v = (k0 + kkb + 0 < 300) ? W[(size_t)(k0 + kkb + 0) * 64 + colB] : 0.f; t0 = f2bf(v);
            v = (k0 + kkb + 1 < 300) ? W[(size_t)(k0 + kkb + 1) * 64 + colB] : 0.f; t1 = f2bf(v);
            v = (k0 + kkb + 2 < 300) ? W[(size_t)(k0 + kkb + 2) * 64 + colB] : 0.f; t2 = f2bf(v);
            v = (k0 + kkb + 3 < 300) ? W[(size_t)(k0 + kkb + 3) * 64 + colB] : 0.f; t3 = f2bf(v);
            v = (k0 + kkb + 4 < 300) ? W[(size_t)(k0 + kkb + 4) * 64 + colB] : 0.f; t4 = f2bf(v);
            v = (k0 + kkb + 5 < 300) ? W[(size_t)(k0 + kkb + 5) * 64 + colB] : 0.f; t5 = f2bf(v);
            v = (k0 + kkb + 6 < 300) ? W[(size_t)(k0 + kkb + 6) * 64 + colB] : 0.f; t6 = f2bf(v);
            v = (k0 + kkb + 7 < 300) ? W[(size_t)(k0 + kkb + 7) * 64 + colB] : 0.f; t7 = f2bf(v);
            *(ushort4*)&B_lds[colB * 40 + kkb]     = make_ushort4(t0, t1, t2, t3);
            *(ushort4*)&B_lds[colB * 40 + kkb + 4] = make_ushort4(t4, t5, t6, t7);
        }
        __syncthreads();
        short8 af[2], bfr[4];
#pragma unroll
        for (int rt = 0; rt < 2; rt++)
            af[rt] = *(const short8*)&A_lds[(wv * 32 + rt * 16 + l15) * 40 + quad * 8];
#pragma unroll
        for (int ct = 0; ct < 4; ct++)
            bfr[ct] = *(const short8*)&B_lds[(ct * 16 + l15) * 40 + quad * 8];
#pragma unroll
        for (int rt = 0; rt < 2; rt++)
#pragma unroll
            for (int ct = 0; ct < 4; ct++)
                acc[rt][ct] = __builtin_amdgcn_mfma_f32_16x16x32_bf16(af[rt], bfr[ct], acc[rt][ct], 0, 0, 0);
        __syncthreads();
    }

    float as_v[4], ad_v[4];
#pragma unroll
    for (int ct = 0; ct < 4; ct++) {
        as_v[ct] = asrc[ct * 16 + l15];
        ad_v[ct] = adst[ct * 16 + l15];
    }
#pragma unroll
    for (int rt = 0; rt < 2; rt++) {
#pragma unroll
        for (int reg = 0; reg < 4; reg++) {
            int row = rowBase + wv * 32 + rt * 16 + quad * 4 + reg;
            bool ok = (row < N);
#pragma unroll
            for (int ct = 0; ct < 4; ct++) {
                float v = acc[rt][ct][reg];
                if (ok) hbf[(size_t)row * 64 + ct * 16 + l15] = f2bf(v);
                float ps = v * as_v[ct];
                float pd = v * ad_v[ct];
                ps += __shfl_xor(ps, 1); ps += __shfl_xor(ps, 2); ps += __shfl_xor(ps, 4);
                pd += __shfl_xor(pd, 1); pd += __shfl_xor(pd, 2); pd += __shfl_xor(pd, 4);
                if ((lane & 7) == 0 && ok) {
                    int head = 2 * ct + ((lane >> 3) & 1);
                    es[row * 8 + head] = ps;
                    ed[row * 8 + head] = pd;
                }
            }
        }
    }
}

// ---------------- GEMM 2 (MFMA bf16): h2(bf16) = h1p(bf16) @ W2, fused scalar e_src/e_dst ----------------

__global__ __launch_bounds__(256) void gemm2_mfma_kernel(
    const unsigned short* __restrict__ xin, const float* __restrict__ W,
    const float* __restrict__ asrc, const float* __restrict__ adst,
    unsigned short* __restrict__ hbf, float* __restrict__ es, float* __restrict__ ed, int N) {
    __shared__ __align__(16) unsigned short A_lds[128 * 72];
    __shared__ __align__(16) unsigned short B_lds[64 * 72];
    const int tx = threadIdx.x;
    const int wv = tx >> 6;
    const int lane = tx & 63;
    const int l15 = lane & 15;
    const int quad = lane >> 4;
    const int rowBase = blockIdx.x * 128;

    f32x4 acc[2][4];
#pragma unroll
    for (int rt = 0; rt < 2; rt++)
#pragma unroll
        for (int ct = 0; ct < 4; ct++) acc[rt][ct] = (f32x4){0.f, 0.f, 0.f, 0.f};

    // stage B: full 64x64 (transposed into [col][k], stride 72)
    {
        int colB = tx & 63;
        int kk = (tx >> 6) * 16;
#pragma unroll
        for (int j = 0; j < 16; j++)
            B_lds[colB * 72 + kk + j] = f2bf(W[(size_t)(kk + j) * 64 + colB]);
    }
    // stage A: 128 rows x 64 k, bf16 input -> straight copy (ushort8 = 16B loads)
    {
        int kq = tx & 7, r0 = tx >> 3;
        const ushort8 z = (ushort8){0, 0, 0, 0, 0, 0, 0, 0};
#pragma unroll
        for (int p = 0; p < 4; p++) {
            int row = p * 32 + r0;
            int grow = rowBase + row;
            ushort8 v = z;
            if (grow < N) v = *(const ushort8*)&xin[(size_t)grow * 64 + kq * 8];
            *(ushort8*)&A_lds[row * 72 + kq * 8] = v;
        }
    }
    __syncthreads();
#pragma unroll
    for (int c = 0; c < 2; c++) {
        short8 af[2], bfr[4];
#pragma unroll
        for (int rt = 0; rt < 2; rt++)
            af[rt] = *(const short8*)&A_lds[(wv * 32 + rt * 16 + l15) * 72 + quad * 8 + c * 32];
#pragma unroll
        for (int ct = 0; ct < 4; ct++)
            bfr[ct] = *(const short8*)&B_lds[(ct * 16 + l15) * 72 + quad * 8 + c * 32];
#pragma unroll
        for (int rt = 0; rt < 2; rt++)
#pragma unroll
            for (int ct = 0; ct < 4; ct++)
                acc[rt][ct] = __builtin_amdgcn_mfma_f32_16x16x32_bf16(af[rt], bfr[ct], acc[rt][ct], 0, 0, 0);
    }

    float as_v[4], ad_v[4];
#pragma unroll
    for (int ct = 0; ct < 4; ct++) {
        as_v[ct] = asrc[ct * 16 + l15];
        ad_v[ct] = adst[ct * 16 + l15];
    }
#pragma unroll
    for (int rt = 0; rt < 2; rt++) {
#pragma unroll
        for (int reg = 0; reg < 4; reg++) {
            int row = rowBase + wv * 32 + rt * 16 + quad * 4 + reg;
            bool ok = (row < N);
            float ps = 0.f, pd = 0.f;
#pragma unroll
            for (int ct = 0; ct < 4; ct++) {
                float v = acc[rt][ct][reg];
                if (ok) hbf[(size_t)row * 64 + ct * 16 + l15] = f2bf(v);
                ps = fmaf(v, as_v[ct], ps);
                pd = fmaf(v, ad_v[ct], pd);
            }
            ps += __shfl_xor(ps, 1); ps += __shfl_xor(ps, 2);
            ps += __shfl_xor(ps, 4); ps += __shfl_xor(ps, 8);
            pd += __shfl_xor(pd, 1); pd += __shfl_xor(pd, 2);
            pd += __shfl_xor(pd, 4); pd += __shfl_xor(pd, 8);
            if (l15 == 0 && ok) { es[row] = ps; ed[row] = pd; }
        }
    }
}

// ---------------- alpha precompute: single pass, no max (logits bounded; softmax shift-invariant) ----------------

__global__ __launch_bounds__(256) void alpha1_kernel(
    const int* __restrict__ rowptr, const int* __restrict__ col,
    const float* __restrict__ es, const float* __restrict__ ed,
    unsigned short* __restrict__ w1a, float* __restrict__ rden, int N) {
    int tid = blockIdx.x * 256 + threadIdx.x;
    int node = tid >> 3, head = tid & 7;
    if (node >= N) return;
    int beg = rowptr[node], end = rowptr[node + 1];
    float edv = ed[node * 8 + head];
    float l = 0.f;
    for (int e = beg; e < end; e++) {
        int s = col[e];
        float v = es[s * 8 + head] + edv;
        v = (v > 0.f) ? v : 0.2f * v;
        v = fminf(v, 30.f);
        float wj = __expf(v);
        l += wj;
        w1a[e * 8 + head] = f2bf(wj);
    }
    rden[node * 8 + head] = 1.f / l;
}

__global__ __launch_bounds__(256) void alpha2_kernel(
    const int* __restrict__ rowptr, const int* __restrict__ col,
    const float* __restrict__ es, const float* __restrict__ ed,
    float* __restrict__ w2a, float* __restrict__ rden, int N) {
    int node = blockIdx.x * 256 + threadIdx.x;
    if (node >= N) return;
    int beg = rowptr[node], end = rowptr[node + 1];
    float edv = ed[node];
    float l = 0.f;
    for (int e = beg; e < end; e++) {
        float v = es[col[e]] + edv;
        v = (v > 0.f) ? v : 0.2f * v;
        v = fminf(v, 30.f);
        float wj = __expf(v);
        l += wj;
        w2a[e] = wj;
    }
    rden[node] = 1.f / l;
}

// ---------------- gather-only aggregations: bf16 h, 2 edges per wave ----------------
// lane = 32*half + fl; lane handles features {2fl, 2fl+1} of edge (i + 2j + half).

__global__ __launch_bounds__(256) void agg1g_kernel(
    const int* __restrict__ rowptr, const int* __restrict__ col,
    const unsigned short* __restrict__ hbf, const unsigned short* __restrict__ w1a,
    const float* __restrict__ rden, const float* __restrict__ b,
    unsigned int* __restrict__ outbf, int N) {
    int node = blockIdx.x * 4 + (threadIdx.x >> 6);
    int lane = threadIdx.x & 63;
    if (node >= N) return;
    int half = lane >> 5, fl = lane & 31;
    int f0 = fl * 2, hh = fl >> 2;
    int beg = rowptr[node], end = rowptr[node + 1];
    float rinv = rden[node * 8 + hh];
    float acc0 = 0.f, acc1 = 0.f;
    for (int i = beg; i < end; i += 16) {
        int ei_[EB], ss[EB];
        float wv[EB];
        unsigned hp[EB];
#pragma unroll
        for (int j = 0; j < EB; j++) ei_[j] = i + 2 * j + half;
#pragma unroll
        for (int j = 0; j < EB; j++) ss[j] = col[ei_[j]];             // col padded by 16
#pragma unroll
        for (int j = 0; j < EB; j++) wv[j] = bf2f(w1a[ei_[j] * 8 + hh]);
#pragma unroll
        for (int j = 0; j < EB; j++) hp[j] = *(const unsigned*)&hbf[(size_t)ss[j] * 64 + f0];
#pragma unroll
        for (int j = 0; j < EB; j++) wv[j] = (ei_[j] < end) ? wv[j] : 0.f;
#pragma unroll
        for (int j = 0; j < EB; j++) {
            float lo = __uint_as_float(hp[j] << 16);
            float hi = __uint_as_float(hp[j] & 0xFFFF0000u);
            acc0 = fmaf(wv[j], lo, acc0);
            acc1 = fmaf(wv[j], hi, acc1);
        }
    }
    acc0 += __shfl_xor(acc0, 32);
    acc1 += __shfl_xor(acc1, 32);
    float o0 = acc0 * rinv + b[f0];
    float o1 = acc1 * rinv + b[f0 + 1];
    o0 = (o0 > 0.f) ? o0 : expm1f(o0);
    o1 = (o1 > 0.f) ? o1 : expm1f(o1);
    if (half == 0) {
        unsigned pk = (unsigned)f2bf(o0) | ((unsigned)f2bf(o1) << 16);
        outbf[((size_t)node * 64 + f0) >> 1] = pk;
    }
}

__global__ __launch_bounds__(256) void agg2g_kernel(
    const int* __restrict__ rowptr, const int* __restrict__ col,
    const unsigned short* __restrict__ hbf, const float* __restrict__ w2a,
    const float* __restrict__ rden, const float* __restrict__ b,
    float* __restrict__ out, int N) {
    int node = blockIdx.x * 4 + (threadIdx.x >> 6);
    int lane = threadIdx.x & 63;
    if (node >= N) return;
    int half = lane >> 5, fl = lane & 31;
    int f0 = fl * 2;
    int beg = rowptr[node], end = rowptr[node + 1];
    float rinv = rden[node];
    float acc0 = 0.f, acc1 = 0.f;
    for (int i = beg; i < end; i += 16) {
        int ei_[EB], ss[EB];
        float wv[EB];
        unsigned hp[EB];
#pragma unroll
        for (int j = 0; j < EB; j++) ei_[j] = i + 2 * j + half;
#pragma unroll
        for (int j = 0; j < EB; j++) ss[j] = col[ei_[j]];
#pragma unroll
        for (int j = 0; j < EB; j++) wv[j] = w2a[ei_[j]];
#pragma unroll
        for (int j = 0; j < EB; j++) hp[j] = *(const unsigned*)&hbf[(size_t)ss[j] * 64 + f0];
#pragma unroll
        for (int j = 0; j < EB; j++) wv[j] = (ei_[j] < end) ? wv[j] : 0.f;
#pragma unroll
        for (int j = 0; j < EB; j++) {
            float lo = __uint_as_float(hp[j] << 16);
            float hi = __uint_as_float(hp[j] & 0xFFFF0000u);
            acc0 = fmaf(wv[j], lo, acc0);
            acc1 = fmaf(wv[j], hi, acc1);
        }
    }
    acc0 += __shfl_xor(acc0, 32);
    acc1 += __shfl_xor(acc1, 32);
    float o0 = acc0 * rinv + b[f0];
    float o1 = acc1 * rinv + b[f0 + 1];
    // log_softmax over 64 features (each half holds all 32 feature-pairs after combine)
    float M = fmaxf(o0, o1);
    M = fmaxf(M, __shfl_xor(M, 1));  M = fmaxf(M, __shfl_xor(M, 2));
    M = fmaxf(M, __shfl_xor(M, 4));  M = fmaxf(M, __shfl_xor(M, 8));
    M = fmaxf(M, __shfl_xor(M, 16));
    float se = __expf(o0 - M) + __expf(o1 - M);
    se += __shfl_xor(se, 1);  se += __shfl_xor(se, 2);
    se += __shfl_xor(se, 4);  se += __shfl_xor(se, 8);
    se += __shfl_xor(se, 16);
    float ls = logf(se);
    if (half == 0) {
        float2 r = make_float2(o0 - M - ls, o1 - M - ls);
        *(float2*)&out[(size_t)node * 64 + f0] = r;
    }
}

// ---------------- launch ----------------

extern "C" void kernel_launch(void* const* d_in, const int* in_sizes, int n_in,
                              void* d_out, int out_size, void* d_ws, size_t ws_size,
                              hipStream_t stream) {
    const float* x   = (const float*)d_in[0];
    const int*   ei  = (const int*)d_in[1];
    const float* W1  = (const float*)d_in[2];
    const float* as1 = (const float*)d_in[3];
    const float* ad1 = (const float*)d_in[4];
    const float* b1  = (const float*)d_in[5];
    const float* W2  = (const float*)d_in[6];
    const float* as2 = (const float*)d_in[7];
    const float* ad2 = (const float*)d_in[8];
    const float* b2  = (const float*)d_in[9];
    const int N = in_sizes[0] / 300;
    const int E = in_sizes[1] / 2;
    const int Etot = E + N;
    const int nbuck = (N + 127) >> 7;   // <= 800
    (void)n_in; (void)out_size; (void)ws_size;

    char* w = (char*)d_ws;
    auto alloc = [&](size_t bytes) -> char* {
        char* p = w;
        w += (bytes + 255) & ~(size_t)255;
        return p;
    };
    int*   flag        = (int*)alloc(256);
    int*   hist        = (int*)alloc((size_t)NBLKS * BPAD * 4);
    int*   bucketTotal = (int*)alloc((size_t)(BPAD + 1) * 4);
    int*   bucketBase  = (int*)alloc((size_t)(BPAD + 1) * 4);
    int*   tmp         = (int*)alloc((size_t)(Etot + 16) * 4);   // reused as w2a
    int*   rowptr      = (int*)alloc((size_t)(N + 1) * 4);
    int*   col         = (int*)alloc((size_t)(Etot + 16) * 4);
    unsigned short* h1  = (unsigned short*)alloc((size_t)N * 64 * 2);
    unsigned short* h1p = (unsigned short*)alloc((size_t)N * 64 * 2);
    float* es1         = (float*)alloc((size_t)N * 8 * 4);
    float* ed1         = (float*)alloc((size_t)N * 8 * 4);
    float* es2         = (float*)alloc((size_t)N * 4);
    float* ed2         = (float*)alloc((size_t)N * 4);
    unsigned short* w1a = (unsigned short*)alloc((size_t)(Etot + 16) * 8 * 2);
    float* rden1       = (float*)alloc((size_t)N * 8 * 4);
    float* rden2       = (float*)alloc((size_t)N * 4);
    unsigned short* h2 = h1;        // h1 dead after agg1
    float* w2a = (float*)tmp;       // tmp dead after binC

    detect64_kernel<<<1, 256, 0, stream>>>(ei, E, flag);

    int chunk = (Etot + NBLKS - 1) / NBLKS;
    binA_kernel<<<NBLKS, 256, 0, stream>>>(ei, E, N, flag, nbuck, hist, chunk);
    scanBlocks_kernel<<<(nbuck + 255) / 256, 256, 0, stream>>>(hist, nbuck, bucketTotal);
    scanBucket_kernel<<<1, 1024, 0, stream>>>(bucketTotal, nbuck, bucketBase);
    binB_kernel<<<NBLKS, 256, 0, stream>>>(ei, E, N, flag, nbuck, hist, bucketBase, tmp, chunk);
    binC_kernel<<<nbuck, 256, 0, stream>>>(tmp, bucketBase, nbuck, N, Etot, rowptr, col);

    gemm1_mfma_kernel<<<(N + 127) / 128, 256, 0, stream>>>(x, W1, as1, ad1, h1, es1, ed1, N);
    alpha1_kernel<<<(N * 8 + 255) / 256, 256, 0, stream>>>(rowptr, col, es1, ed1, w1a, rden1, N);
    agg1g_kernel<<<(N + 3) / 4, 256, 0, stream>>>(rowptr, col, h1, w1a, rden1, b1,
                                                  (unsigned int*)h1p, N);
    gemm2_mfma_kernel<<<(N + 127) / 128, 256, 0, stream>>>(h1p, W2, as2, ad2, h2, es2, ed2, N);
    alpha2_kernel<<<(N + 255) / 256, 256, 0, stream>>>(rowptr, col, es2, ed2, w2a, rden2, N);
    agg2g_kernel<<<(N + 3) / 4, 256, 0, stream>>>(rowptr, col, h2, w2a, rden2, b2, (float*)d_out, N);
}

// Round 7
// 437.458 us; speedup vs baseline: 1.2474x; 1.0962x over previous
//
#include <hip/hip_runtime.h>
#include <math.h>

using short8  = __attribute__((ext_vector_type(8))) short;
using ushort8 = __attribute__((ext_vector_type(8))) unsigned short;
using f32x4   = __attribute__((ext_vector_type(4))) float;

#define NBLKS 512
#define BPAD  800   // padded bucket count (nbuck <= 800)
#define EB 8

__device__ __forceinline__ unsigned short f2bf(float f) {
    unsigned u = __float_as_uint(f);
    unsigned r = u + 0x7FFF + ((u >> 16) & 1);   // round-to-nearest-even
    return (unsigned short)(r >> 16);
}
__device__ __forceinline__ float bf2f(unsigned short v) {
    return __uint_as_float((unsigned)v << 16);
}

// ---------------- edge dtype detect ----------------

__global__ void detect64_kernel(const int* __restrict__ ei, int E, int* __restrict__ flag) {
    __shared__ int any;
    if (threadIdx.x == 0) any = 0;
    __syncthreads();
    for (int i = threadIdx.x; i < 1024; i += 256) {
        if (ei[2 * i + 1] != 0) { any = 1; break; }
    }
    __syncthreads();
    if (threadIdx.x == 0) *flag = (any ? 0 : 1);  // 1 => int64
}

// ---------------- CSR build: two-level counting sort, zero global atomics ----------------

__global__ __launch_bounds__(256) void binA_kernel(
    const int* __restrict__ ei, int E, int N, const int* __restrict__ flag,
    int nbuck, int* __restrict__ hist, int chunk) {
    __shared__ int lh[BPAD];
    for (int i = threadIdx.x; i < nbuck; i += 256) lh[i] = 0;
    __syncthreads();
    int is64 = *flag;
    int Etot = E + N;
    int beg = blockIdx.x * chunk, end = min(Etot, beg + chunk);
    for (int i = beg + threadIdx.x; i < end; i += 256) {
        int d = (i < E) ? (is64 ? ei[2 * (E + i)] : ei[E + i]) : (i - E);
        atomicAdd(&lh[d >> 7], 1);
    }
    __syncthreads();
    for (int i = threadIdx.x; i < nbuck; i += 256) hist[blockIdx.x * BPAD + i] = lh[i];
}

__global__ void scanBlocks_kernel(int* __restrict__ hist, int nbuck, int* __restrict__ bucketTotal) {
    int bin = blockIdx.x * 256 + threadIdx.x;
    if (bin >= nbuck) return;
    int run = 0;
    for (int b = 0; b < NBLKS; b++) {
        int v = hist[b * BPAD + bin];
        hist[b * BPAD + bin] = run;
        run += v;
    }
    bucketTotal[bin] = run;
}

__global__ void scanBucket_kernel(const int* __restrict__ bucketTotal, int nbuck,
                                  int* __restrict__ bucketBase) {
    __shared__ int s[1024];
    int t = threadIdx.x;
    int v = (t < nbuck) ? bucketTotal[t] : 0;
    s[t] = v;
    __syncthreads();
    for (int off = 1; off < 1024; off <<= 1) {
        int x = (t >= off) ? s[t - off] : 0;
        __syncthreads();
        s[t] += x;
        __syncthreads();
    }
    if (t < nbuck) bucketBase[t] = s[t] - v;
    if (t == nbuck - 1) bucketBase[nbuck] = s[t];
}

__global__ __launch_bounds__(256) void binB_kernel(
    const int* __restrict__ ei, int E, int N, const int* __restrict__ flag,
    int nbuck, const int* __restrict__ hist, const int* __restrict__ bucketBase,
    int* __restrict__ tmp, int chunk) {
    __shared__ int cur[BPAD];
    for (int i = threadIdx.x; i < nbuck; i += 256)
        cur[i] = bucketBase[i] + hist[blockIdx.x * BPAD + i];
    __syncthreads();
    int is64 = *flag;
    int Etot = E + N;
    int beg = blockIdx.x * chunk, end = min(Etot, beg + chunk);
    for (int i = beg + threadIdx.x; i < end; i += 256) {
        int s, d;
        if (i < E) {
            if (is64) { s = ei[2 * i]; d = ei[2 * (E + i)]; }
            else      { s = ei[i];     d = ei[E + i]; }
        } else { s = i - E; d = i - E; }
        int pos = atomicAdd(&cur[d >> 7], 1);
        tmp[pos] = ((d & 127) << 17) | s;   // src < 2^17
    }
}

__global__ __launch_bounds__(256) void binC_kernel(
    const int* __restrict__ tmp, const int* __restrict__ bucketBase, int nbuck,
    int N, int Etot, int* __restrict__ rowptr, int* __restrict__ col) {
    __shared__ int lh[128];
    __shared__ int cur[128];
    int g = blockIdx.x;
    int t = threadIdx.x;
    int beg = bucketBase[g], end = bucketBase[g + 1];
    if (t < 128) lh[t] = 0;
    __syncthreads();
    for (int i = beg + t; i < end; i += 256) atomicAdd(&lh[tmp[i] >> 17], 1);
    __syncthreads();
    int c = (t < 128) ? lh[t] : 0;
    for (int off = 1; off < 128; off <<= 1) {
        int x = 0;
        if (t < 128 && t >= off) x = lh[t - off];
        __syncthreads();
        if (t < 128) lh[t] += x;
        __syncthreads();
    }
    if (t < 128) {
        int excl = lh[t] - c;
        cur[t] = beg + excl;
        int node = g * 128 + t;
        if (node < N) rowptr[node] = beg + excl;
    }
    if (g == 0 && t == 0) rowptr[N] = Etot;
    if (g == 0 && t < 16) col[Etot + t] = 0;   // pad so agg can read past end safely
    __syncthreads();
    for (int i = beg + t; i < end; i += 256) {
        int v = tmp[i];
        int pos = atomicAdd(&cur[v >> 17], 1);
        col[pos] = v & 0x1FFFF;
    }
}

// ---------------- GEMM 1 (MFMA bf16): h1(bf16) = x @ W1, fused e_src/e_dst ----------------

__global__ __launch_bounds__(256) void gemm1_mfma_kernel(
    const float* __restrict__ x, const float* __restrict__ W,
    const float* __restrict__ asrc, const float* __restrict__ adst,
    unsigned short* __restrict__ hbf, float* __restrict__ es, float* __restrict__ ed, int N) {
    __shared__ __align__(16) unsigned short A_lds[128 * 40];
    __shared__ __align__(16) unsigned short B_lds[64 * 40];
    const int tx = threadIdx.x;
    const int wv = tx >> 6;
    const int lane = tx & 63;
    const int l15 = lane & 15;
    const int quad = lane >> 4;
    const int rowBase = blockIdx.x * 128;

    f32x4 acc[2][4];
#pragma unroll
    for (int rt = 0; rt < 2; rt++)
#pragma unroll
        for (int ct = 0; ct < 4; ct++) acc[rt][ct] = (f32x4){0.f, 0.f, 0.f, 0.f};

    const int kq = tx & 7;
    const int r0 = tx >> 3;
    const int colB = tx & 63;
    const int kkb = (tx >> 6) * 8;

    for (int k0 = 0; k0 < 320; k0 += 32) {
        bool kvalid = (k0 + kq * 4 + 4 <= 300);
#pragma unroll
        for (int p = 0; p < 4; p++) {
            int row = p * 32 + r0;
            int grow = rowBase + row;
            float4 v = make_float4(0.f, 0.f, 0.f, 0.f);
            if (kvalid && grow < N) v = *(const float4*)&x[(size_t)grow * 300 + k0 + kq * 4];
            *(ushort4*)&A_lds[row * 40 + kq * 4] =
                make_ushort4(f2bf(v.x), f2bf(v.y), f2bf(v.z), f2bf(v.w));
        }
        {
            unsigned short t0, t1, t2, t3, t4, t5, t6, t7;
            float v;
            v = (k0 + kkb + 0 < 300) ? W[(size_t)(k0 + kkb + 0) * 64 + colB] : 0.f; t0 = f2bf(v);
            v = (k0 + kkb + 1 < 300) ? W[(size_t)(k0 + kkb + 1) * 64 + colB] : 0.f; t1 = f2bf(v);
            v = (k0 + kkb + 2 < 300) ? W[(size_t)(k0 + kkb + 2) * 64 + colB] : 0.f; t2 = f2bf(v);
            v = (k0 + kkb + 3 < 300) ? W[(size_t)(k0 + kkb + 3) * 64 + colB] : 0.f; t3 = f2bf(v);
            v = (k0 + kkb + 4 < 300) ? W[(size_t)(k0 + kkb + 4) * 64 + colB] : 0.f; t4 = f2bf(v);
            v = (k0 + kkb + 5 < 300) ? W[(size_t)(k0 + kkb + 5) * 64 + colB] : 0.f; t5 = f2bf(v);
            v = (k0 + kkb + 6 < 300) ? W[(size_t)(k0 + kkb + 6) * 64 + colB] : 0.f; t6 = f2bf(v);
            v = (k0 + kkb + 7 < 300) ? W[(size_t)(k0 + kkb + 7) * 64 + colB] : 0.f; t7 = f2bf(v);
            *(ushort4*)&B_lds[colB * 40 + kkb]     = make_ushort4(t0, t1, t2, t3);
            *(ushort4*)&B_lds[colB * 40 + kkb + 4] = make_ushort4(t4, t5, t6, t7);
        }
        __syncthreads();
        short8 af[2], bfr[4];
#pragma unroll
        for (int rt = 0; rt < 2; rt++)
            af[rt] = *(const short8*)&A_lds[(wv * 32 + rt * 16 + l15) * 40 + quad * 8];
#pragma unroll
        for (int ct = 0; ct < 4; ct++)
            bfr[ct] = *(const short8*)&B_lds[(ct * 16 + l15) * 40 + quad * 8];
#pragma unroll
        for (int rt = 0; rt < 2; rt++)
#pragma unroll
            for (int ct = 0; ct < 4; ct++)
                acc[rt][ct] = __builtin_amdgcn_mfma_f32_16x16x32_bf16(af[rt], bfr[ct], acc[rt][ct], 0, 0, 0);
        __syncthreads();
    }

    float as_v[4], ad_v[4];
#pragma unroll
    for (int ct = 0; ct < 4; ct++) {
        as_v[ct] = asrc[ct * 16 + l15];
        ad_v[ct] = adst[ct * 16 + l15];
    }
#pragma unroll
    for (int rt = 0; rt < 2; rt++) {
#pragma unroll
        for (int reg = 0; reg < 4; reg++) {
            int row = rowBase + wv * 32 + rt * 16 + quad * 4 + reg;
            bool ok = (row < N);
#pragma unroll
            for (int ct = 0; ct < 4; ct++) {
                float v = acc[rt][ct][reg];
                if (ok) hbf[(size_t)row * 64 + ct * 16 + l15] = f2bf(v);
                float ps = v * as_v[ct];
                float pd = v * ad_v[ct];
                ps += __shfl_xor(ps, 1); ps += __shfl_xor(ps, 2); ps += __shfl_xor(ps, 4);
                pd += __shfl_xor(pd, 1); pd += __shfl_xor(pd, 2); pd += __shfl_xor(pd, 4);
                if ((lane & 7) == 0 && ok) {
                    int head = 2 * ct + ((lane >> 3) & 1);
                    es[row * 8 + head] = ps;
                    ed[row * 8 + head] = pd;
                }
            }
        }
    }
}

// ---------------- GEMM 2 (MFMA bf16): h2(bf16) = h1p(bf16) @ W2, fused scalar e_src/e_dst ----------------

__global__ __launch_bounds__(256) void gemm2_mfma_kernel(
    const unsigned short* __restrict__ xin, const float* __restrict__ W,
    const float* __restrict__ asrc, const float* __restrict__ adst,
    unsigned short* __restrict__ hbf, float* __restrict__ es, float* __restrict__ ed, int N) {
    __shared__ __align__(16) unsigned short A_lds[128 * 72];
    __shared__ __align__(16) unsigned short B_lds[64 * 72];
    const int tx = threadIdx.x;
    const int wv = tx >> 6;
    const int lane = tx & 63;
    const int l15 = lane & 15;
    const int quad = lane >> 4;
    const int rowBase = blockIdx.x * 128;

    f32x4 acc[2][4];
#pragma unroll
    for (int rt = 0; rt < 2; rt++)
#pragma unroll
        for (int ct = 0; ct < 4; ct++) acc[rt][ct] = (f32x4){0.f, 0.f, 0.f, 0.f};

    // stage B: full 64x64 (transposed into [col][k], stride 72)
    {
        int colB = tx & 63;
        int kk = (tx >> 6) * 16;
#pragma unroll
        for (int j = 0; j < 16; j++)
            B_lds[colB * 72 + kk + j] = f2bf(W[(size_t)(kk + j) * 64 + colB]);
    }
    // stage A: 128 rows x 64 k, bf16 input -> straight copy (ushort8 = 16B loads)
    {
        int kq = tx & 7, r0 = tx >> 3;
        const ushort8 z = (ushort8){0, 0, 0, 0, 0, 0, 0, 0};
#pragma unroll
        for (int p = 0; p < 4; p++) {
            int row = p * 32 + r0;
            int grow = rowBase + row;
            ushort8 v = z;
            if (grow < N) v = *(const ushort8*)&xin[(size_t)grow * 64 + kq * 8];
            *(ushort8*)&A_lds[row * 72 + kq * 8] = v;
        }
    }
    __syncthreads();
#pragma unroll
    for (int c = 0; c < 2; c++) {
        short8 af[2], bfr[4];
#pragma unroll
        for (int rt = 0; rt < 2; rt++)
            af[rt] = *(const short8*)&A_lds[(wv * 32 + rt * 16 + l15) * 72 + quad * 8 + c * 32];
#pragma unroll
        for (int ct = 0; ct < 4; ct++)
            bfr[ct] = *(const short8*)&B_lds[(ct * 16 + l15) * 72 + quad * 8 + c * 32];
#pragma unroll
        for (int rt = 0; rt < 2; rt++)
#pragma unroll
            for (int ct = 0; ct < 4; ct++)
                acc[rt][ct] = __builtin_amdgcn_mfma_f32_16x16x32_bf16(af[rt], bfr[ct], acc[rt][ct], 0, 0, 0);
    }

    float as_v[4], ad_v[4];
#pragma unroll
    for (int ct = 0; ct < 4; ct++) {
        as_v[ct] = asrc[ct * 16 + l15];
        ad_v[ct] = adst[ct * 16 + l15];
    }
#pragma unroll
    for (int rt = 0; rt < 2; rt++) {
#pragma unroll
        for (int reg = 0; reg < 4; reg++) {
            int row = rowBase + wv * 32 + rt * 16 + quad * 4 + reg;
            bool ok = (row < N);
            float ps = 0.f, pd = 0.f;
#pragma unroll
            for (int ct = 0; ct < 4; ct++) {
                float v = acc[rt][ct][reg];
                if (ok) hbf[(size_t)row * 64 + ct * 16 + l15] = f2bf(v);
                ps = fmaf(v, as_v[ct], ps);
                pd = fmaf(v, ad_v[ct], pd);
            }
            ps += __shfl_xor(ps, 1); ps += __shfl_xor(ps, 2);
            ps += __shfl_xor(ps, 4); ps += __shfl_xor(ps, 8);
            pd += __shfl_xor(pd, 1); pd += __shfl_xor(pd, 2);
            pd += __shfl_xor(pd, 4); pd += __shfl_xor(pd, 8);
            if (l15 == 0 && ok) { es[row] = ps; ed[row] = pd; }
        }
    }
}

// ---------------- fused aggregations: softmax weights computed inline ----------------
// lane = 32*half + fl; lane handles features {2fl, 2fl+1} of edge (i + 2j + half).
// Softmax shift dropped (logits bounded, clamp at 30); denominator accumulated inline.

__global__ __launch_bounds__(256) void agg1f_kernel(
    const int* __restrict__ rowptr, const int* __restrict__ col,
    const unsigned short* __restrict__ hbf, const float* __restrict__ es,
    const float* __restrict__ ed, const float* __restrict__ b,
    unsigned int* __restrict__ outbf, int N) {
    int node = blockIdx.x * 4 + (threadIdx.x >> 6);
    int lane = threadIdx.x & 63;
    if (node >= N) return;
    int half = lane >> 5, fl = lane & 31;
    int f0 = fl * 2, hh = fl >> 2;
    int beg = rowptr[node], end = rowptr[node + 1];
    float edv = ed[node * 8 + hh];
    float acc0 = 0.f, acc1 = 0.f, lsum = 0.f;
    for (int i = beg; i < end; i += 16) {
        int ei_[EB], ss[EB];
        float ev[EB];
        unsigned hp[EB];
#pragma unroll
        for (int j = 0; j < EB; j++) ei_[j] = i + 2 * j + half;
#pragma unroll
        for (int j = 0; j < EB; j++) ss[j] = col[ei_[j]];             // col padded by 16
#pragma unroll
        for (int j = 0; j < EB; j++) ev[j] = es[ss[j] * 8 + hh];
#pragma unroll
        for (int j = 0; j < EB; j++) hp[j] = *(const unsigned*)&hbf[(size_t)ss[j] * 64 + f0];
#pragma unroll
        for (int j = 0; j < EB; j++) {
            float e = ev[j] + edv;
            e = (e > 0.f) ? e : 0.2f * e;
            float wj = __expf(fminf(e, 30.f));
            wj = (ei_[j] < end) ? wj : 0.f;
            lsum += wj;
            float lo = __uint_as_float(hp[j] << 16);
            float hi = __uint_as_float(hp[j] & 0xFFFF0000u);
            acc0 = fmaf(wj, lo, acc0);
            acc1 = fmaf(wj, hi, acc1);
        }
    }
    acc0 += __shfl_xor(acc0, 32);
    acc1 += __shfl_xor(acc1, 32);
    lsum += __shfl_xor(lsum, 32);
    float rinv = 1.f / lsum;
    float o0 = acc0 * rinv + b[f0];
    float o1 = acc1 * rinv + b[f0 + 1];
    o0 = (o0 > 0.f) ? o0 : expm1f(o0);
    o1 = (o1 > 0.f) ? o1 : expm1f(o1);
    if (half == 0) {
        unsigned pk = (unsigned)f2bf(o0) | ((unsigned)f2bf(o1) << 16);
        outbf[((size_t)node * 64 + f0) >> 1] = pk;
    }
}

__global__ __launch_bounds__(256) void agg2f_kernel(
    const int* __restrict__ rowptr, const int* __restrict__ col,
    const unsigned short* __restrict__ hbf, const float* __restrict__ es,
    const float* __restrict__ ed, const float* __restrict__ b,
    float* __restrict__ out, int N) {
    int node = blockIdx.x * 4 + (threadIdx.x >> 6);
    int lane = threadIdx.x & 63;
    if (node >= N) return;
    int half = lane >> 5, fl = lane & 31;
    int f0 = fl * 2;
    int beg = rowptr[node], end = rowptr[node + 1];
    float edv = ed[node];
    float acc0 = 0.f, acc1 = 0.f, lsum = 0.f;
    for (int i = beg; i < end; i += 16) {
        int ei_[EB], ss[EB];
        float ev[EB];
        unsigned hp[EB];
#pragma unroll
        for (int j = 0; j < EB; j++) ei_[j] = i + 2 * j + half;
#pragma unroll
        for (int j = 0; j < EB; j++) ss[j] = col[ei_[j]];
#pragma unroll
        for (int j = 0; j < EB; j++) ev[j] = es[ss[j]];
#pragma unroll
        for (int j = 0; j < EB; j++) hp[j] = *(const unsigned*)&hbf[(size_t)ss[j] * 64 + f0];
#pragma unroll
        for (int j = 0; j < EB; j++) {
            float e = ev[j] + edv;
            e = (e > 0.f) ? e : 0.2f * e;
            float wj = __expf(fminf(e, 30.f));
            wj = (ei_[j] < end) ? wj : 0.f;
            lsum += wj;
            float lo = __uint_as_float(hp[j] << 16);
            float hi = __uint_as_float(hp[j] & 0xFFFF0000u);
            acc0 = fmaf(wj, lo, acc0);
            acc1 = fmaf(wj, hi, acc1);
        }
    }
    acc0 += __shfl_xor(acc0, 32);
    acc1 += __shfl_xor(acc1, 32);
    lsum += __shfl_xor(lsum, 32);
    float rinv = 1.f / lsum;
    float o0 = acc0 * rinv + b[f0];
    float o1 = acc1 * rinv + b[f0 + 1];
    // log_softmax over 64 features (each half holds all 32 feature-pairs after combine)
    float M = fmaxf(o0, o1);
    M = fmaxf(M, __shfl_xor(M, 1));  M = fmaxf(M, __shfl_xor(M, 2));
    M = fmaxf(M, __shfl_xor(M, 4));  M = fmaxf(M, __shfl_xor(M, 8));
    M = fmaxf(M, __shfl_xor(M, 16));
    float se = __expf(o0 - M) + __expf(o1 - M);
    se += __shfl_xor(se, 1);  se += __shfl_xor(se, 2);
    se += __shfl_xor(se, 4);  se += __shfl_xor(se, 8);
    se += __shfl_xor(se, 16);
    float ls = logf(se);
    if (half == 0) {
        float2 r = make_float2(o0 - M - ls, o1 - M - ls);
        *(float2*)&out[(size_t)node * 64 + f0] = r;
    }
}

// ---------------- launch ----------------

extern "C" void kernel_launch(void* const* d_in, const int* in_sizes, int n_in,
                              void* d_out, int out_size, void* d_ws, size_t ws_size,
                              hipStream_t stream) {
    const float* x   = (const float*)d_in[0];
    const int*   ei  = (const int*)d_in[1];
    const float* W1  = (const float*)d_in[2];
    const float* as1 = (const float*)d_in[3];
    const float* ad1 = (const float*)d_in[4];
    const float* b1  = (const float*)d_in[5];
    const float* W2  = (const float*)d_in[6];
    const float* as2 = (const float*)d_in[7];
    const float* ad2 = (const float*)d_in[8];
    const float* b2  = (const float*)d_in[9];
    const int N = in_sizes[0] / 300;
    const int E = in_sizes[1] / 2;
    const int Etot = E + N;
    const int nbuck = (N + 127) >> 7;   // <= 800
    (void)n_in; (void)out_size; (void)ws_size;

    char* w = (char*)d_ws;
    auto alloc = [&](size_t bytes) -> char* {
        char* p = w;
        w += (bytes + 255) & ~(size_t)255;
        return p;
    };
    int*   flag        = (int*)alloc(256);
    int*   hist        = (int*)alloc((size_t)NBLKS * BPAD * 4);
    int*   bucketTotal = (int*)alloc((size_t)(BPAD + 1) * 4);
    int*   bucketBase  = (int*)alloc((size_t)(BPAD + 1) * 4);
    int*   tmp         = (int*)alloc((size_t)(Etot + 16) * 4);
    int*   rowptr      = (int*)alloc((size_t)(N + 1) * 4);
    int*   col         = (int*)alloc((size_t)(Etot + 16) * 4);
    unsigned short* h1  = (unsigned short*)alloc((size_t)N * 64 * 2);
    unsigned short* h1p = (unsigned short*)alloc((size_t)N * 64 * 2);
    float* es1         = (float*)alloc((size_t)N * 8 * 4);
    float* ed1         = (float*)alloc((size_t)N * 8 * 4);
    float* es2         = (float*)alloc((size_t)N * 4);
    float* ed2         = (float*)alloc((size_t)N * 4);
    unsigned short* h2 = h1;        // h1 dead after agg1

    detect64_kernel<<<1, 256, 0, stream>>>(ei, E, flag);

    int chunk = (Etot + NBLKS - 1) / NBLKS;
    binA_kernel<<<NBLKS, 256, 0, stream>>>(ei, E, N, flag, nbuck, hist, chunk);
    scanBlocks_kernel<<<(nbuck + 255) / 256, 256, 0, stream>>>(hist, nbuck, bucketTotal);
    scanBucket_kernel<<<1, 1024, 0, stream>>>(bucketTotal, nbuck, bucketBase);
    binB_kernel<<<NBLKS, 256, 0, stream>>>(ei, E, N, flag, nbuck, hist, bucketBase, tmp, chunk);
    binC_kernel<<<nbuck, 256, 0, stream>>>(tmp, bucketBase, nbuck, N, Etot, rowptr, col);

    gemm1_mfma_kernel<<<(N + 127) / 128, 256, 0, stream>>>(x, W1, as1, ad1, h1, es1, ed1, N);
    agg1f_kernel<<<(N + 3) / 4, 256, 0, stream>>>(rowptr, col, h1, es1, ed1, b1,
                                                  (unsigned int*)h1p, N);
    gemm2_mfma_kernel<<<(N + 127) / 128, 256, 0, stream>>>(h1p, W2, as2, ad2, h2, es2, ed2, N);
    agg2f_kernel<<<(N + 3) / 4, 256, 0, stream>>>(rowptr, col, h2, es2, ed2, b2, (float*)d_out, N);
}